// Round 15
// baseline (293.225 us; speedup 1.0000x reference)
//
#include <hip/hip_runtime.h>
#include <hip/hip_bf16.h>
#include <math.h>

#define NN 10000
#define NE 160000

typedef __attribute__((ext_vector_type(8))) _Float16 f16x8;
typedef __attribute__((ext_vector_type(4))) _Float16 f16x4;
typedef __attribute__((ext_vector_type(4))) float f32x4;

static __device__ __forceinline__ void gload_lds16(const _Float16* g, _Float16* l) {
  __builtin_amdgcn_global_load_lds((const __attribute__((address_space(1))) char*)g,
                                   (__attribute__((address_space(3))) char*)l, 16, 0, 0);
}

// ---------------- CSR build ----------------
__global__ __launch_bounds__(1024) void scan_kernel(const int* __restrict__ counts,
                                                    int* __restrict__ row_ptr,
                                                    int* __restrict__ cursor, int N) {
  __shared__ int sums[1024];
  int t = threadIdx.x;
  const int CH = (N + 1023) >> 10;
  int base = t * CH;
  int s = 0;
  for (int i = 0; i < CH; ++i) { int idx = base + i; if (idx < N) s += counts[idx]; }
  sums[t] = s;
  __syncthreads();
  for (int off = 1; off < 1024; off <<= 1) {
    int v = 0;
    if (t >= off) v = sums[t - off];
    __syncthreads();
    if (t >= off) sums[t] += v;
    __syncthreads();
  }
  int run = (t == 0) ? 0 : sums[t - 1];
  for (int i = 0; i < CH; ++i) {
    int idx = base + i;
    if (idx < N) { row_ptr[idx] = run; cursor[idx] = run; run += counts[idx]; }
  }
  if (t == 0) row_ptr[N] = sums[1023];
}

__global__ void scatter_kernel(const int* __restrict__ src, const int* __restrict__ dst,
                               int* __restrict__ cursor, int* __restrict__ ssrc, int E) {
  int e = blockIdx.x * blockDim.x + threadIdx.x;
  if (e < E) {
    int pos = atomicAdd(&cursor[dst[e]], 1);
    ssrc[pos] = src[e];
  }
}

// ---------------- prep2: LDS-tiled weight transposes + x copy + edge count ----------------
#define TB_W2 256
#define TB_W3 192
#define TB_W1 16
#define TB_T (TB_W2 + TB_W3 + TB_W1)          // 464
#define TB_X ((NN * 64) / 256)                // 2500
#define TB_E ((NE + 255) / 256)               // 625
__global__ __launch_bounds__(256) void prep2(const float* __restrict__ x,
                                             const float* __restrict__ W1,
                                             const float* __restrict__ W2,
                                             const float* __restrict__ W3,
                                             const int* __restrict__ dst,
                                             int* __restrict__ counts,
                                             _Float16* __restrict__ xh,
                                             _Float16* __restrict__ w1,
                                             _Float16* __restrict__ w2,
                                             _Float16* __restrict__ w3) {
  int b = blockIdx.x;
  int t = threadIdx.x;
  if (b < TB_T) {
    const float* S;
    _Float16* D;
    int K, Nsrc, KP, k0, n0;
    if (b < TB_W2) {
      S = W2; D = w2; K = 1024; Nsrc = 1024; KP = 1024;
      k0 = (b & 15) * 64; n0 = (b >> 4) * 64;
    } else if (b < TB_W2 + TB_W3) {
      int bb = b - TB_W2;
      S = W3; D = w3; K = 1024; Nsrc = 726; KP = 1024;
      k0 = (bb & 15) * 64; n0 = (bb >> 4) * 64;
    } else {
      int bb = b - TB_W2 - TB_W3;
      S = W1; D = w1; K = 50; Nsrc = 1024; KP = 64;
      k0 = 0; n0 = bb * 64;
    }
    __shared__ float tile[64][65];
#pragma unroll
    for (int i = 0; i < 16; ++i) {
      int idx = i * 256 + t;
      int r = idx >> 6, c = idx & 63;
      int gk = k0 + r, gn = n0 + c;
      tile[r][c] = (gk < K && gn < Nsrc) ? S[(size_t)gk * Nsrc + gn] : 0.f;
    }
    __syncthreads();
#pragma unroll
    for (int i = 0; i < 16; ++i) {
      int idx = i * 256 + t;
      int r = idx >> 6, c = idx & 63;
      D[(size_t)(n0 + r) * KP + k0 + c] = (_Float16)tile[c][r];
    }
    return;
  }
  int i = (b - TB_T) * 256 + t;
  if (i < NN * 64) {
    int m = i >> 6, k = i & 63;
    xh[i] = (_Float16)(k < 50 ? x[m * 50 + k] : 0.f);
    return;
  }
  i -= NN * 64;
  if (i < NE) atomicAdd(&counts[dst[i]], 1);
}

// ---------------- fp16 MFMA GEMM, XCD-swizzled, 128x128 tile, BK=64 ----------------
template<int PAD121>
__global__ __launch_bounds__(256) void gemm_f16(const _Float16* __restrict__ A,
                                                const _Float16* __restrict__ B,
                                                _Float16* __restrict__ C,
                                                int M, int KP, int NC) {
  int flat = blockIdx.x;
  int xcd = flat & 7;
  int slot = flat >> 3;
  int cblk = slot % NC;
  int rblk = (slot / NC) * 8 + xcd;
  const int m0 = rblk * 128;
  if (m0 >= M) return;
  const int n0 = cblk * 128;

  __shared__ _Float16 As[128 * 64];
  __shared__ _Float16 Bs[128 * 64];

  const int t = threadIdx.x;
  const int lane = t & 63;
  const int wid = t >> 6;
  const int wr = wid >> 1;
  const int wc = wid & 1;
  const int row_in = lane & 15;
  const int kgrp = lane >> 4;

  const int srow = wid * 32 + ((lane >> 3) & 7);
  const int sl7 = lane & 7;

  f32x4 acc[4][4];
#pragma unroll
  for (int i = 0; i < 4; ++i)
#pragma unroll
    for (int j = 0; j < 4; ++j) acc[i][j] = (f32x4){0.f, 0.f, 0.f, 0.f};

  for (int k0 = 0; k0 < KP; k0 += 64) {
    if (k0) __syncthreads();
#pragma unroll
    for (int j = 0; j < 4; ++j) {
      int row = srow + j * 8;
      int gs = (sl7 ^ (row & 7)) * 8;
      int gm = m0 + row;
      if (gm >= M) gm = M - 1;
      _Float16* ldsA = &As[(wid * 32 + j * 8) * 64];
      _Float16* ldsB = &Bs[(wid * 32 + j * 8) * 64];
      gload_lds16(&A[(size_t)gm * KP + k0 + gs], ldsA);
      gload_lds16(&B[(size_t)(n0 + row) * KP + k0 + gs], ldsB);
    }
    __syncthreads();

#pragma unroll
    for (int ks = 0; ks < 2; ++ks) {
      f16x8 a[4], b[4];
#pragma unroll
      for (int mi = 0; mi < 4; ++mi) {
        int arow = wr * 64 + mi * 16 + row_in;
        int ps = ((kgrp + ks * 4) ^ (arow & 7)) * 8;
        a[mi] = *(const f16x8*)&As[arow * 64 + ps];
      }
#pragma unroll
      for (int ni = 0; ni < 4; ++ni) {
        int brow = wc * 64 + ni * 16 + row_in;
        int ps = ((kgrp + ks * 4) ^ (brow & 7)) * 8;
        b[ni] = *(const f16x8*)&Bs[brow * 64 + ps];
      }
#pragma unroll
      for (int mi = 0; mi < 4; ++mi)
#pragma unroll
        for (int ni = 0; ni < 4; ++ni)
          acc[mi][ni] = __builtin_amdgcn_mfma_f32_16x16x32_f16(a[mi], b[ni], acc[mi][ni], 0, 0, 0);
    }
  }

#pragma unroll
  for (int mi = 0; mi < 4; ++mi) {
#pragma unroll
    for (int ni = 0; ni < 4; ++ni) {
      int gn = n0 + wc * 64 + ni * 16 + row_in;
#pragma unroll
      for (int j = 0; j < 4; ++j) {
        int gm = m0 + wr * 64 + mi * 16 + kgrp * 4 + j;
        if (gm >= M) continue;
        if (PAD121) {
          if (gn < 726) {
            int h = gn / 121;
            int pc = h * 128 + (gn - h * 121);
            C[(size_t)gm * 768 + pc] = (_Float16)acc[mi][ni][j];
          }
        } else {
          C[(size_t)gm * 1024 + gn] = (_Float16)acc[mi][ni][j];
        }
      }
    }
  }
}

// ---------------- attention scores from fp16 Wh (head stride HS, row stride SW) ----------------
template<int H, int F, int SW, int HS>
__global__ void att_kernel(const _Float16* __restrict__ Whb, const float* __restrict__ a,
                           float* __restrict__ att_s, float* __restrict__ att_d, int N) {
  int n = blockIdx.x;
  int h = threadIdx.x >> 6;
  int lane = threadIdx.x & 63;
  const _Float16* w = Whb + (size_t)n * SW + h * HS;
  const float* as = a + (size_t)h * 2 * F;
  const float* ad = as + F;
  float ss = 0.f, sd = 0.f;
  if (F == 256) {
    f16x4 wv = *(const f16x4*)&w[lane * 4];
    f32x4 av = *(const f32x4*)&as[lane * 4];
    f32x4 dv = *(const f32x4*)&ad[lane * 4];
#pragma unroll
    for (int j = 0; j < 4; ++j) {
      float v = (float)wv[j];
      ss += v * av[j];
      sd += v * dv[j];
    }
  } else {
    for (int f = lane; f < F; f += 64) {
      float v = (float)w[f];
      ss += v * as[f];
      sd += v * ad[f];
    }
  }
#pragma unroll
  for (int off = 32; off > 0; off >>= 1) {
    ss += __shfl_down(ss, off);
    sd += __shfl_down(sd, off);
  }
  if (lane == 0) {
    att_s[n * H + h] = ss;
    att_d[n * H + h] = sd;
  }
}

// ---------------- fused CSR edge softmax: 16 lanes/node, 16 nodes per block ----------------
template<int H>
__global__ __launch_bounds__(256) void edge_softmax_csr(const int* __restrict__ row_ptr,
                                                        const int* __restrict__ ssrc,
                                                        const float* __restrict__ att_s,
                                                        const float* __restrict__ att_d,
                                                        float* __restrict__ cbuf,
                                                        float* __restrict__ dinv, int N) {
  int n = blockIdx.x * 16 + (threadIdx.x >> 4);
  if (n >= N) return;
  int lane = threadIdx.x & 15;
  int beg = row_ptr[n], end = row_ptr[n + 1];

  float ad[H];
  if (H == 4) {
    f32x4 v = *(const f32x4*)&att_d[n * 4];
    ad[0] = v.x; ad[1] = v.y; ad[2] = v.z; ad[3] = v.w;
  } else {
#pragma unroll
    for (int h = 0; h < H; ++h) ad[h] = att_d[n * H + h];
  }

  float m[H];
#pragma unroll
  for (int h = 0; h < H; ++h) m[h] = -1e30f;
  for (int k = beg + lane; k < end; k += 16) {
    int s = ssrc[k];
    float as[H];
    if (H == 4) {
      f32x4 v = *(const f32x4*)&att_s[s * 4];
      as[0] = v.x; as[1] = v.y; as[2] = v.z; as[3] = v.w;
    } else {
#pragma unroll
      for (int h = 0; h < H; ++h) as[h] = att_s[s * H + h];
    }
#pragma unroll
    for (int h = 0; h < H; ++h) {
      float xv = as[h] + ad[h];
      float l = xv >= 0.f ? xv : 0.2f * xv;
      m[h] = fmaxf(m[h], l);
    }
  }
#pragma unroll
  for (int h = 0; h < H; ++h)
#pragma unroll
    for (int off = 8; off > 0; off >>= 1) m[h] = fmaxf(m[h], __shfl_xor(m[h], off));

  float sum[H];
#pragma unroll
  for (int h = 0; h < H; ++h) sum[h] = 0.f;
  for (int k = beg + lane; k < end; k += 16) {
    int s = ssrc[k];
    float as[H];
    if (H == 4) {
      f32x4 v = *(const f32x4*)&att_s[s * 4];
      as[0] = v.x; as[1] = v.y; as[2] = v.z; as[3] = v.w;
    } else {
#pragma unroll
      for (int h = 0; h < H; ++h) as[h] = att_s[s * H + h];
    }
    float ev[H];
#pragma unroll
    for (int h = 0; h < H; ++h) {
      float xv = as[h] + ad[h];
      float l = xv >= 0.f ? xv : 0.2f * xv;
      ev[h] = __expf(l - m[h]);
      sum[h] += ev[h];
    }
    if (H == 4) {
      *(f32x4*)&cbuf[(size_t)k * 4] = (f32x4){ev[0], ev[1], ev[2], ev[3]};
    } else {
#pragma unroll
      for (int h = 0; h < H; ++h) cbuf[(size_t)k * H + h] = ev[h];
    }
  }
#pragma unroll
  for (int h = 0; h < H; ++h) {
#pragma unroll
    for (int off = 8; off > 0; off >>= 1) sum[h] += __shfl_xor(sum[h], off);
  }
  if (lane < H) dinv[n * H + lane] = 1.f / (sum[lane] + 1e-16f);
}

// ---------------- chunked aggregate, concat layers (H=4,F=256): 64 lanes/node ----------------
// Four 16-lane quarters process edges k ≡ beg+q (mod 4), each unroll x4 ->
// up to 16 gathers in flight per node; combine via shfl_xor(16) + shfl_xor(32).
template<int MODE>
__global__ __launch_bounds__(256) void aggregate_cat_chunk(const int* __restrict__ row_ptr,
                                                           const int* __restrict__ ssrc,
                                                           const float* __restrict__ cbuf,
                                                           const float* __restrict__ dinv,
                                                           const _Float16* __restrict__ Whb,
                                                           const _Float16* __restrict__ h1,
                                                           _Float16* __restrict__ outv, int N) {
  int b = blockIdx.x;
  int chunk = b & 7;
  int group = b >> 3;
  int n = group * 4 + (threadIdx.x >> 6);
  if (n >= N) return;
  int l64 = threadIdx.x & 63;
  int quarter = l64 >> 4;
  int tt = l64 & 15;
  int idx = chunk * 128 + tt * 8;
  int h = chunk >> 1;
  float inv = dinv[n * 4 + h];

  float acc[8] = {};
  int beg = row_ptr[n], end = row_ptr[n + 1];
  int k = beg + quarter;
  for (; k + 12 < end; k += 16) {
    int s0 = ssrc[k], s1 = ssrc[k + 4], s2 = ssrc[k + 8], s3 = ssrc[k + 12];
    float c0 = cbuf[(size_t)k * 4 + h];
    float c1 = cbuf[(size_t)(k + 4) * 4 + h];
    float c2 = cbuf[(size_t)(k + 8) * 4 + h];
    float c3 = cbuf[(size_t)(k + 12) * 4 + h];
    f16x8 w0 = *(const f16x8*)&Whb[(size_t)s0 * 1024 + idx];
    f16x8 w1 = *(const f16x8*)&Whb[(size_t)s1 * 1024 + idx];
    f16x8 w2 = *(const f16x8*)&Whb[(size_t)s2 * 1024 + idx];
    f16x8 w3 = *(const f16x8*)&Whb[(size_t)s3 * 1024 + idx];
#pragma unroll
    for (int j = 0; j < 8; ++j) {
      acc[j] += c0 * (float)w0[j];
      acc[j] += c1 * (float)w1[j];
      acc[j] += c2 * (float)w2[j];
      acc[j] += c3 * (float)w3[j];
    }
  }
  for (; k < end; k += 4) {
    int s0 = ssrc[k];
    float c0 = cbuf[(size_t)k * 4 + h];
    f16x8 w0 = *(const f16x8*)&Whb[(size_t)s0 * 1024 + idx];
#pragma unroll
    for (int j = 0; j < 8; ++j) acc[j] += c0 * (float)w0[j];
  }
#pragma unroll
  for (int j = 0; j < 8; ++j) {
    acc[j] += __shfl_xor(acc[j], 16);
    acc[j] += __shfl_xor(acc[j], 32);
  }

  if (quarter == 0) {
    size_t o = (size_t)n * 1024 + idx;
    f16x8 r1;
    if (MODE == 1) r1 = *(const f16x8*)&h1[o];
    f16x8 vo;
#pragma unroll
    for (int j = 0; j < 8; ++j) {
      float v = acc[j] * inv;
      v = v > 0.f ? v : expm1f(v);
      if (MODE == 1) v += (float)r1[j];
      vo[j] = (_Float16)v;
    }
    *(f16x8*)&outv[o] = vo;
  }
}

// ---------------- chunked aggregate, mean layer: chunk = head (6 of 8), 64 lanes/node ----------------
__global__ __launch_bounds__(256) void aggregate_mean_chunk(const int* __restrict__ row_ptr,
                                                            const int* __restrict__ ssrc,
                                                            const float* __restrict__ cbuf,
                                                            const float* __restrict__ dinv,
                                                            const _Float16* __restrict__ Whb,
                                                            float* __restrict__ part, int N) {
  int b = blockIdx.x;
  int h = b & 7;
  if (h >= 6) return;
  int n = (b >> 3) * 4 + (threadIdx.x >> 6);
  if (n >= N) return;
  int l64 = threadIdx.x & 63;
  int quarter = l64 >> 4;
  int tt = l64 & 15;
  int base = h * 128 + tt * 8;
  float inv = dinv[n * 6 + h];

  float acc[8] = {};
  int beg = row_ptr[n], end = row_ptr[n + 1];
  int k = beg + quarter;
  for (; k + 12 < end; k += 16) {
    int s0 = ssrc[k], s1 = ssrc[k + 4], s2 = ssrc[k + 8], s3 = ssrc[k + 12];
    float c0 = cbuf[(size_t)k * 6 + h];
    float c1 = cbuf[(size_t)(k + 4) * 6 + h];
    float c2 = cbuf[(size_t)(k + 8) * 6 + h];
    float c3 = cbuf[(size_t)(k + 12) * 6 + h];
    f16x8 w0 = *(const f16x8*)&Whb[(size_t)s0 * 768 + base];
    f16x8 w1 = *(const f16x8*)&Whb[(size_t)s1 * 768 + base];
    f16x8 w2 = *(const f16x8*)&Whb[(size_t)s2 * 768 + base];
    f16x8 w3 = *(const f16x8*)&Whb[(size_t)s3 * 768 + base];
#pragma unroll
    for (int j = 0; j < 8; ++j) {
      acc[j] += c0 * (float)w0[j];
      acc[j] += c1 * (float)w1[j];
      acc[j] += c2 * (float)w2[j];
      acc[j] += c3 * (float)w3[j];
    }
  }
  for (; k < end; k += 4) {
    int s0 = ssrc[k];
    float c0 = cbuf[(size_t)k * 6 + h];
    f16x8 w0 = *(const f16x8*)&Whb[(size_t)s0 * 768 + base];
#pragma unroll
    for (int j = 0; j < 8; ++j) acc[j] += c0 * (float)w0[j];
  }
#pragma unroll
  for (int j = 0; j < 8; ++j) {
    acc[j] += __shfl_xor(acc[j], 16);
    acc[j] += __shfl_xor(acc[j], 32);
  }

  if (quarter == 0) {
    float* p = &part[(size_t)n * 768 + base];
    *(f32x4*)&p[0] = (f32x4){acc[0] * inv, acc[1] * inv, acc[2] * inv, acc[3] * inv};
    *(f32x4*)&p[4] = (f32x4){acc[4] * inv, acc[5] * inv, acc[6] * inv, acc[7] * inv};
  }
}

// ---------------- reduce 6 head-slices -> out[n][121] ----------------
__global__ __launch_bounds__(128) void reduce_mean(const float* __restrict__ part,
                                                   float* __restrict__ out, int N) {
  int n = blockIdx.x;
  int f = threadIdx.x;
  if (f >= 121) return;
  const float* p = &part[(size_t)n * 768];
  float s = 0.f;
#pragma unroll
  for (int h = 0; h < 6; ++h) s += p[h * 128 + f];
  out[(size_t)n * 121 + f] = s * (1.0f / 6.0f);
}

extern "C" void kernel_launch(void* const* d_in, const int* in_sizes, int n_in,
                              void* d_out, int out_size, void* d_ws, size_t ws_size,
                              hipStream_t stream) {
  const float* x  = (const float*)d_in[0];
  const int* eidx = (const int*)d_in[1];
  const float* W1 = (const float*)d_in[2];
  const float* a1 = (const float*)d_in[3];
  const float* W2 = (const float*)d_in[4];
  const float* a2 = (const float*)d_in[5];
  const float* W3 = (const float*)d_in[6];
  const float* a3 = (const float*)d_in[7];
  float* out = (float*)d_out;

  const int N = NN, E = NE;
  const int* src = eidx;
  const int* dst = eidx + E;

  char* ws = (char*)d_ws;
  size_t off = 0;
  auto alloc = [&](size_t bytes) -> void* {
    void* p = ws + off;
    off += (bytes + 255) & ~(size_t)255;
    return p;
  };
  _Float16* Whf  = (_Float16*)alloc((size_t)N * 1024 * 2);
  _Float16* h1   = (_Float16*)alloc((size_t)N * 1024 * 2);
  _Float16* hsum = (_Float16*)alloc((size_t)N * 1024 * 2);
  _Float16* xh   = (_Float16*)alloc((size_t)N * 64 * 2);
  _Float16* w1   = (_Float16*)alloc((size_t)1024 * 64 * 2);
  _Float16* w2   = (_Float16*)alloc((size_t)1024 * 1024 * 2);
  _Float16* w3   = (_Float16*)alloc((size_t)768 * 1024 * 2);
  float* cbuf  = (float*)alloc((size_t)E * 6 * 4);
  float* part  = (float*)alloc((size_t)N * 768 * 4);
  float* atts  = (float*)alloc((size_t)N * 6 * 4);
  float* attd  = (float*)alloc((size_t)N * 6 * 4);
  float* dinv  = (float*)alloc((size_t)N * 6 * 4);
  int* counts  = (int*)alloc((size_t)N * 4);
  int* row_ptr = (int*)alloc((size_t)(N + 1) * 4);
  int* cursor  = (int*)alloc((size_t)N * 4);
  int* ssrc    = (int*)alloc((size_t)E * 4);

  // ---- prep (tiled transposes + x + edge count) and CSR ----
  hipMemsetAsync(counts, 0, (size_t)N * 4, stream);
  prep2<<<TB_T + TB_X + TB_E, 256, 0, stream>>>(x, W1, W2, W3, dst, counts, xh, w1, w2, w3);
  scan_kernel<<<1, 1024, 0, stream>>>(counts, row_ptr, cursor, N);
  scatter_kernel<<<(E + 255) / 256, 256, 0, stream>>>(src, dst, cursor, ssrc, E);

  const int RPG = 10;                         // ceil(79 row-blocks / 8 XCDs)
  const int AGG_GRID = 8 * ((N + 3) / 4);     // 8 chunks x node-groups (4 nodes/block)
  const int SM_GRID = (N + 15) / 16;          // 16 nodes per block

  // ---- layer 1 ----
  gemm_f16<0><<<8 * RPG * 8, 256, 0, stream>>>(xh, w1, Whf, N, 64, 8);
  att_kernel<4, 256, 1024, 256><<<N, 256, 0, stream>>>(Whf, a1, atts, attd, N);
  edge_softmax_csr<4><<<SM_GRID, 256, 0, stream>>>(row_ptr, ssrc, atts, attd, cbuf, dinv, N);
  aggregate_cat_chunk<0><<<AGG_GRID, 256, 0, stream>>>(row_ptr, ssrc, cbuf, dinv, Whf, nullptr, h1, N);

  // ---- layer 2 (aggregate emits hsum = h1 + elu(agg)) ----
  gemm_f16<0><<<8 * RPG * 8, 256, 0, stream>>>(h1, w2, Whf, N, 1024, 8);
  att_kernel<4, 256, 1024, 256><<<N, 256, 0, stream>>>(Whf, a2, atts, attd, N);
  edge_softmax_csr<4><<<SM_GRID, 256, 0, stream>>>(row_ptr, ssrc, atts, attd, cbuf, dinv, N);
  aggregate_cat_chunk<1><<<AGG_GRID, 256, 0, stream>>>(row_ptr, ssrc, cbuf, dinv, Whf, h1, hsum, N);

  // ---- layer 3 (padded head-stride 128; partials + reduce) ----
  gemm_f16<1><<<8 * RPG * 6, 256, 0, stream>>>(hsum, w3, Whf, N, 1024, 6);
  att_kernel<6, 121, 768, 128><<<N, 384, 0, stream>>>(Whf, a3, atts, attd, N);
  edge_softmax_csr<6><<<SM_GRID, 256, 0, stream>>>(row_ptr, ssrc, atts, attd, cbuf, dinv, N);
  aggregate_mean_chunk<<<AGG_GRID, 256, 0, stream>>>(row_ptr, ssrc, cbuf, dinv, Whf, part, N);
  reduce_mean<<<N, 128, 0, stream>>>(part, out, N);
}

// Round 16
// 263.762 us; speedup vs baseline: 1.1117x; 1.1117x over previous
//
#include <hip/hip_runtime.h>
#include <hip/hip_bf16.h>
#include <math.h>

#define NN 10000
#define NE 160000

typedef __attribute__((ext_vector_type(8))) _Float16 f16x8;
typedef __attribute__((ext_vector_type(4))) _Float16 f16x4;
typedef __attribute__((ext_vector_type(4))) float f32x4;

static __device__ __forceinline__ void gload_lds16(const _Float16* g, _Float16* l) {
  __builtin_amdgcn_global_load_lds((const __attribute__((address_space(1))) char*)g,
                                   (__attribute__((address_space(3))) char*)l, 16, 0, 0);
}

// ---------------- CSR build ----------------
__global__ __launch_bounds__(1024) void scan_kernel(const int* __restrict__ counts,
                                                    int* __restrict__ row_ptr,
                                                    int* __restrict__ cursor, int N) {
  __shared__ int sums[1024];
  int t = threadIdx.x;
  const int CH = (N + 1023) >> 10;
  int base = t * CH;
  int s = 0;
  for (int i = 0; i < CH; ++i) { int idx = base + i; if (idx < N) s += counts[idx]; }
  sums[t] = s;
  __syncthreads();
  for (int off = 1; off < 1024; off <<= 1) {
    int v = 0;
    if (t >= off) v = sums[t - off];
    __syncthreads();
    if (t >= off) sums[t] += v;
    __syncthreads();
  }
  int run = (t == 0) ? 0 : sums[t - 1];
  for (int i = 0; i < CH; ++i) {
    int idx = base + i;
    if (idx < N) { row_ptr[idx] = run; cursor[idx] = run; run += counts[idx]; }
  }
  if (t == 0) row_ptr[N] = sums[1023];
}

__global__ void scatter_kernel(const int* __restrict__ src, const int* __restrict__ dst,
                               int* __restrict__ cursor, int* __restrict__ ssrc, int E) {
  int e = blockIdx.x * blockDim.x + threadIdx.x;
  if (e < E) {
    int pos = atomicAdd(&cursor[dst[e]], 1);
    ssrc[pos] = src[e];
  }
}

// ---------------- prep2: LDS-tiled weight transposes + x copy + edge count ----------------
#define TB_W2 256
#define TB_W3 192
#define TB_W1 16
#define TB_T (TB_W2 + TB_W3 + TB_W1)          // 464
#define TB_X ((NN * 64) / 256)                // 2500
#define TB_E ((NE + 255) / 256)               // 625
__global__ __launch_bounds__(256) void prep2(const float* __restrict__ x,
                                             const float* __restrict__ W1,
                                             const float* __restrict__ W2,
                                             const float* __restrict__ W3,
                                             const int* __restrict__ dst,
                                             int* __restrict__ counts,
                                             _Float16* __restrict__ xh,
                                             _Float16* __restrict__ w1,
                                             _Float16* __restrict__ w2,
                                             _Float16* __restrict__ w3) {
  int b = blockIdx.x;
  int t = threadIdx.x;
  if (b < TB_T) {
    const float* S;
    _Float16* D;
    int K, Nsrc, KP, k0, n0;
    if (b < TB_W2) {
      S = W2; D = w2; K = 1024; Nsrc = 1024; KP = 1024;
      k0 = (b & 15) * 64; n0 = (b >> 4) * 64;
    } else if (b < TB_W2 + TB_W3) {
      int bb = b - TB_W2;
      S = W3; D = w3; K = 1024; Nsrc = 726; KP = 1024;
      k0 = (bb & 15) * 64; n0 = (bb >> 4) * 64;
    } else {
      int bb = b - TB_W2 - TB_W3;
      S = W1; D = w1; K = 50; Nsrc = 1024; KP = 64;
      k0 = 0; n0 = bb * 64;
    }
    __shared__ float tile[64][65];
#pragma unroll
    for (int i = 0; i < 16; ++i) {
      int idx = i * 256 + t;
      int r = idx >> 6, c = idx & 63;
      int gk = k0 + r, gn = n0 + c;
      tile[r][c] = (gk < K && gn < Nsrc) ? S[(size_t)gk * Nsrc + gn] : 0.f;
    }
    __syncthreads();
#pragma unroll
    for (int i = 0; i < 16; ++i) {
      int idx = i * 256 + t;
      int r = idx >> 6, c = idx & 63;
      D[(size_t)(n0 + r) * KP + k0 + c] = (_Float16)tile[c][r];
    }
    return;
  }
  int i = (b - TB_T) * 256 + t;
  if (i < NN * 64) {
    int m = i >> 6, k = i & 63;
    xh[i] = (_Float16)(k < 50 ? x[m * 50 + k] : 0.f);
    return;
  }
  i -= NN * 64;
  if (i < NE) atomicAdd(&counts[dst[i]], 1);
}

// ---------------- fp16 MFMA GEMM, XCD-swizzled, 128x128 tile, BK=64 ----------------
template<int PAD121>
__global__ __launch_bounds__(256) void gemm_f16(const _Float16* __restrict__ A,
                                                const _Float16* __restrict__ B,
                                                _Float16* __restrict__ C,
                                                int M, int KP, int NC) {
  int flat = blockIdx.x;
  int xcd = flat & 7;
  int slot = flat >> 3;
  int cblk = slot % NC;
  int rblk = (slot / NC) * 8 + xcd;
  const int m0 = rblk * 128;
  if (m0 >= M) return;
  const int n0 = cblk * 128;

  __shared__ _Float16 As[128 * 64];
  __shared__ _Float16 Bs[128 * 64];

  const int t = threadIdx.x;
  const int lane = t & 63;
  const int wid = t >> 6;
  const int wr = wid >> 1;
  const int wc = wid & 1;
  const int row_in = lane & 15;
  const int kgrp = lane >> 4;

  const int srow = wid * 32 + ((lane >> 3) & 7);
  const int sl7 = lane & 7;

  f32x4 acc[4][4];
#pragma unroll
  for (int i = 0; i < 4; ++i)
#pragma unroll
    for (int j = 0; j < 4; ++j) acc[i][j] = (f32x4){0.f, 0.f, 0.f, 0.f};

  for (int k0 = 0; k0 < KP; k0 += 64) {
    if (k0) __syncthreads();
#pragma unroll
    for (int j = 0; j < 4; ++j) {
      int row = srow + j * 8;
      int gs = (sl7 ^ (row & 7)) * 8;
      int gm = m0 + row;
      if (gm >= M) gm = M - 1;
      _Float16* ldsA = &As[(wid * 32 + j * 8) * 64];
      _Float16* ldsB = &Bs[(wid * 32 + j * 8) * 64];
      gload_lds16(&A[(size_t)gm * KP + k0 + gs], ldsA);
      gload_lds16(&B[(size_t)(n0 + row) * KP + k0 + gs], ldsB);
    }
    __syncthreads();

#pragma unroll
    for (int ks = 0; ks < 2; ++ks) {
      f16x8 a[4], b[4];
#pragma unroll
      for (int mi = 0; mi < 4; ++mi) {
        int arow = wr * 64 + mi * 16 + row_in;
        int ps = ((kgrp + ks * 4) ^ (arow & 7)) * 8;
        a[mi] = *(const f16x8*)&As[arow * 64 + ps];
      }
#pragma unroll
      for (int ni = 0; ni < 4; ++ni) {
        int brow = wc * 64 + ni * 16 + row_in;
        int ps = ((kgrp + ks * 4) ^ (brow & 7)) * 8;
        b[ni] = *(const f16x8*)&Bs[brow * 64 + ps];
      }
#pragma unroll
      for (int mi = 0; mi < 4; ++mi)
#pragma unroll
        for (int ni = 0; ni < 4; ++ni)
          acc[mi][ni] = __builtin_amdgcn_mfma_f32_16x16x32_f16(a[mi], b[ni], acc[mi][ni], 0, 0, 0);
    }
  }

#pragma unroll
  for (int mi = 0; mi < 4; ++mi) {
#pragma unroll
    for (int ni = 0; ni < 4; ++ni) {
      int gn = n0 + wc * 64 + ni * 16 + row_in;
#pragma unroll
      for (int j = 0; j < 4; ++j) {
        int gm = m0 + wr * 64 + mi * 16 + kgrp * 4 + j;
        if (gm >= M) continue;
        if (PAD121) {
          if (gn < 726) {
            int h = gn / 121;
            int pc = h * 128 + (gn - h * 121);
            C[(size_t)gm * 768 + pc] = (_Float16)acc[mi][ni][j];
          }
        } else {
          C[(size_t)gm * 1024 + gn] = (_Float16)acc[mi][ni][j];
        }
      }
    }
  }
}

// ---------------- attention scores from fp16 Wh (head stride HS, row stride SW) ----------------
template<int H, int F, int SW, int HS>
__global__ void att_kernel(const _Float16* __restrict__ Whb, const float* __restrict__ a,
                           float* __restrict__ att_s, float* __restrict__ att_d, int N) {
  int n = blockIdx.x;
  int h = threadIdx.x >> 6;
  int lane = threadIdx.x & 63;
  const _Float16* w = Whb + (size_t)n * SW + h * HS;
  const float* as = a + (size_t)h * 2 * F;
  const float* ad = as + F;
  float ss = 0.f, sd = 0.f;
  if (F == 256) {
    f16x4 wv = *(const f16x4*)&w[lane * 4];
    f32x4 av = *(const f32x4*)&as[lane * 4];
    f32x4 dv = *(const f32x4*)&ad[lane * 4];
#pragma unroll
    for (int j = 0; j < 4; ++j) {
      float v = (float)wv[j];
      ss += v * av[j];
      sd += v * dv[j];
    }
  } else {
    for (int f = lane; f < F; f += 64) {
      float v = (float)w[f];
      ss += v * as[f];
      sd += v * ad[f];
    }
  }
#pragma unroll
  for (int off = 32; off > 0; off >>= 1) {
    ss += __shfl_down(ss, off);
    sd += __shfl_down(sd, off);
  }
  if (lane == 0) {
    att_s[n * H + h] = ss;
    att_d[n * H + h] = sd;
  }
}

// ---------------- fused CSR edge softmax: 16 lanes/node, 16 nodes per block ----------------
template<int H>
__global__ __launch_bounds__(256) void edge_softmax_csr(const int* __restrict__ row_ptr,
                                                        const int* __restrict__ ssrc,
                                                        const float* __restrict__ att_s,
                                                        const float* __restrict__ att_d,
                                                        float* __restrict__ cbuf,
                                                        float* __restrict__ dinv, int N) {
  int n = blockIdx.x * 16 + (threadIdx.x >> 4);
  if (n >= N) return;
  int lane = threadIdx.x & 15;
  int beg = row_ptr[n], end = row_ptr[n + 1];

  float ad[H];
  if (H == 4) {
    f32x4 v = *(const f32x4*)&att_d[n * 4];
    ad[0] = v.x; ad[1] = v.y; ad[2] = v.z; ad[3] = v.w;
  } else {
#pragma unroll
    for (int h = 0; h < H; ++h) ad[h] = att_d[n * H + h];
  }

  float m[H];
#pragma unroll
  for (int h = 0; h < H; ++h) m[h] = -1e30f;
  for (int k = beg + lane; k < end; k += 16) {
    int s = ssrc[k];
    float as[H];
    if (H == 4) {
      f32x4 v = *(const f32x4*)&att_s[s * 4];
      as[0] = v.x; as[1] = v.y; as[2] = v.z; as[3] = v.w;
    } else {
#pragma unroll
      for (int h = 0; h < H; ++h) as[h] = att_s[s * H + h];
    }
#pragma unroll
    for (int h = 0; h < H; ++h) {
      float xv = as[h] + ad[h];
      float l = xv >= 0.f ? xv : 0.2f * xv;
      m[h] = fmaxf(m[h], l);
    }
  }
#pragma unroll
  for (int h = 0; h < H; ++h)
#pragma unroll
    for (int off = 8; off > 0; off >>= 1) m[h] = fmaxf(m[h], __shfl_xor(m[h], off));

  float sum[H];
#pragma unroll
  for (int h = 0; h < H; ++h) sum[h] = 0.f;
  for (int k = beg + lane; k < end; k += 16) {
    int s = ssrc[k];
    float as[H];
    if (H == 4) {
      f32x4 v = *(const f32x4*)&att_s[s * 4];
      as[0] = v.x; as[1] = v.y; as[2] = v.z; as[3] = v.w;
    } else {
#pragma unroll
      for (int h = 0; h < H; ++h) as[h] = att_s[s * H + h];
    }
    float ev[H];
#pragma unroll
    for (int h = 0; h < H; ++h) {
      float xv = as[h] + ad[h];
      float l = xv >= 0.f ? xv : 0.2f * xv;
      ev[h] = __expf(l - m[h]);
      sum[h] += ev[h];
    }
    if (H == 4) {
      *(f32x4*)&cbuf[(size_t)k * 4] = (f32x4){ev[0], ev[1], ev[2], ev[3]};
    } else {
#pragma unroll
      for (int h = 0; h < H; ++h) cbuf[(size_t)k * H + h] = ev[h];
    }
  }
#pragma unroll
  for (int h = 0; h < H; ++h) {
#pragma unroll
    for (int off = 8; off > 0; off >>= 1) sum[h] += __shfl_xor(sum[h], off);
  }
  if (lane < H) dinv[n * H + lane] = 1.f / (sum[lane] + 1e-16f);
}

// ---------------- chunked aggregate, concat layers (H=4,F=256): 32 lanes/node ----------------
// Two 16-lane halves process even/odd edges (each unroll x4 -> 8 gathers in flight
// per node); combine partial acc via shfl_xor(.,16); half 0 writes.
template<int MODE>
__global__ __launch_bounds__(256) void aggregate_cat_chunk(const int* __restrict__ row_ptr,
                                                           const int* __restrict__ ssrc,
                                                           const float* __restrict__ cbuf,
                                                           const float* __restrict__ dinv,
                                                           const _Float16* __restrict__ Whb,
                                                           const _Float16* __restrict__ h1,
                                                           _Float16* __restrict__ outv, int N) {
  int b = blockIdx.x;
  int chunk = b & 7;
  int group = b >> 3;
  int n = group * 8 + (threadIdx.x >> 5);
  if (n >= N) return;
  int l32 = threadIdx.x & 31;
  int half = l32 >> 4;
  int tt = l32 & 15;
  int idx = chunk * 128 + tt * 8;
  int h = chunk >> 1;
  float inv = dinv[n * 4 + h];

  float acc[8] = {};
  int beg = row_ptr[n], end = row_ptr[n + 1];
  int k = beg + half;
  for (; k + 6 < end; k += 8) {
    int s0 = ssrc[k], s1 = ssrc[k + 2], s2 = ssrc[k + 4], s3 = ssrc[k + 6];
    float c0 = cbuf[(size_t)k * 4 + h];
    float c1 = cbuf[(size_t)(k + 2) * 4 + h];
    float c2 = cbuf[(size_t)(k + 4) * 4 + h];
    float c3 = cbuf[(size_t)(k + 6) * 4 + h];
    f16x8 w0 = *(const f16x8*)&Whb[(size_t)s0 * 1024 + idx];
    f16x8 w1 = *(const f16x8*)&Whb[(size_t)s1 * 1024 + idx];
    f16x8 w2 = *(const f16x8*)&Whb[(size_t)s2 * 1024 + idx];
    f16x8 w3 = *(const f16x8*)&Whb[(size_t)s3 * 1024 + idx];
#pragma unroll
    for (int j = 0; j < 8; ++j) {
      acc[j] += c0 * (float)w0[j];
      acc[j] += c1 * (float)w1[j];
      acc[j] += c2 * (float)w2[j];
      acc[j] += c3 * (float)w3[j];
    }
  }
  for (; k < end; k += 2) {
    int s0 = ssrc[k];
    float c0 = cbuf[(size_t)k * 4 + h];
    f16x8 w0 = *(const f16x8*)&Whb[(size_t)s0 * 1024 + idx];
#pragma unroll
    for (int j = 0; j < 8; ++j) acc[j] += c0 * (float)w0[j];
  }
#pragma unroll
  for (int j = 0; j < 8; ++j) acc[j] += __shfl_xor(acc[j], 16);

  if (half == 0) {
    size_t o = (size_t)n * 1024 + idx;
    f16x8 r1;
    if (MODE == 1) r1 = *(const f16x8*)&h1[o];
    f16x8 vo;
#pragma unroll
    for (int j = 0; j < 8; ++j) {
      float v = acc[j] * inv;
      v = v > 0.f ? v : expm1f(v);
      if (MODE == 1) v += (float)r1[j];
      vo[j] = (_Float16)v;
    }
    *(f16x8*)&outv[o] = vo;
  }
}

// ---------------- chunked aggregate, mean layer: chunk = head (6 of 8), 32 lanes/node ----------------
__global__ __launch_bounds__(256) void aggregate_mean_chunk(const int* __restrict__ row_ptr,
                                                            const int* __restrict__ ssrc,
                                                            const float* __restrict__ cbuf,
                                                            const float* __restrict__ dinv,
                                                            const _Float16* __restrict__ Whb,
                                                            float* __restrict__ part, int N) {
  int b = blockIdx.x;
  int h = b & 7;
  if (h >= 6) return;
  int n = (b >> 3) * 8 + (threadIdx.x >> 5);
  if (n >= N) return;
  int l32 = threadIdx.x & 31;
  int half = l32 >> 4;
  int tt = l32 & 15;
  int base = h * 128 + tt * 8;
  float inv = dinv[n * 6 + h];

  float acc[8] = {};
  int beg = row_ptr[n], end = row_ptr[n + 1];
  int k = beg + half;
  for (; k + 6 < end; k += 8) {
    int s0 = ssrc[k], s1 = ssrc[k + 2], s2 = ssrc[k + 4], s3 = ssrc[k + 6];
    float c0 = cbuf[(size_t)k * 6 + h];
    float c1 = cbuf[(size_t)(k + 2) * 6 + h];
    float c2 = cbuf[(size_t)(k + 4) * 6 + h];
    float c3 = cbuf[(size_t)(k + 6) * 6 + h];
    f16x8 w0 = *(const f16x8*)&Whb[(size_t)s0 * 768 + base];
    f16x8 w1 = *(const f16x8*)&Whb[(size_t)s1 * 768 + base];
    f16x8 w2 = *(const f16x8*)&Whb[(size_t)s2 * 768 + base];
    f16x8 w3 = *(const f16x8*)&Whb[(size_t)s3 * 768 + base];
#pragma unroll
    for (int j = 0; j < 8; ++j) {
      acc[j] += c0 * (float)w0[j];
      acc[j] += c1 * (float)w1[j];
      acc[j] += c2 * (float)w2[j];
      acc[j] += c3 * (float)w3[j];
    }
  }
  for (; k < end; k += 2) {
    int s0 = ssrc[k];
    float c0 = cbuf[(size_t)k * 6 + h];
    f16x8 w0 = *(const f16x8*)&Whb[(size_t)s0 * 768 + base];
#pragma unroll
    for (int j = 0; j < 8; ++j) acc[j] += c0 * (float)w0[j];
  }
#pragma unroll
  for (int j = 0; j < 8; ++j) acc[j] += __shfl_xor(acc[j], 16);

  if (half == 0) {
    float* p = &part[(size_t)n * 768 + base];
    *(f32x4*)&p[0] = (f32x4){acc[0] * inv, acc[1] * inv, acc[2] * inv, acc[3] * inv};
    *(f32x4*)&p[4] = (f32x4){acc[4] * inv, acc[5] * inv, acc[6] * inv, acc[7] * inv};
  }
}

// ---------------- reduce 6 head-slices -> out[n][121] ----------------
__global__ __launch_bounds__(128) void reduce_mean(const float* __restrict__ part,
                                                   float* __restrict__ out, int N) {
  int n = blockIdx.x;
  int f = threadIdx.x;
  if (f >= 121) return;
  const float* p = &part[(size_t)n * 768];
  float s = 0.f;
#pragma unroll
  for (int h = 0; h < 6; ++h) s += p[h * 128 + f];
  out[(size_t)n * 121 + f] = s * (1.0f / 6.0f);
}

extern "C" void kernel_launch(void* const* d_in, const int* in_sizes, int n_in,
                              void* d_out, int out_size, void* d_ws, size_t ws_size,
                              hipStream_t stream) {
  const float* x  = (const float*)d_in[0];
  const int* eidx = (const int*)d_in[1];
  const float* W1 = (const float*)d_in[2];
  const float* a1 = (const float*)d_in[3];
  const float* W2 = (const float*)d_in[4];
  const float* a2 = (const float*)d_in[5];
  const float* W3 = (const float*)d_in[6];
  const float* a3 = (const float*)d_in[7];
  float* out = (float*)d_out;

  const int N = NN, E = NE;
  const int* src = eidx;
  const int* dst = eidx + E;

  char* ws = (char*)d_ws;
  size_t off = 0;
  auto alloc = [&](size_t bytes) -> void* {
    void* p = ws + off;
    off += (bytes + 255) & ~(size_t)255;
    return p;
  };
  _Float16* Whf  = (_Float16*)alloc((size_t)N * 1024 * 2);
  _Float16* h1   = (_Float16*)alloc((size_t)N * 1024 * 2);
  _Float16* hsum = (_Float16*)alloc((size_t)N * 1024 * 2);
  _Float16* xh   = (_Float16*)alloc((size_t)N * 64 * 2);
  _Float16* w1   = (_Float16*)alloc((size_t)1024 * 64 * 2);
  _Float16* w2   = (_Float16*)alloc((size_t)1024 * 1024 * 2);
  _Float16* w3   = (_Float16*)alloc((size_t)768 * 1024 * 2);
  float* cbuf  = (float*)alloc((size_t)E * 6 * 4);
  float* part  = (float*)alloc((size_t)N * 768 * 4);
  float* atts  = (float*)alloc((size_t)N * 6 * 4);
  float* attd  = (float*)alloc((size_t)N * 6 * 4);
  float* dinv  = (float*)alloc((size_t)N * 6 * 4);
  int* counts  = (int*)alloc((size_t)N * 4);
  int* row_ptr = (int*)alloc((size_t)(N + 1) * 4);
  int* cursor  = (int*)alloc((size_t)N * 4);
  int* ssrc    = (int*)alloc((size_t)E * 4);

  // ---- prep (tiled transposes + x + edge count) and CSR ----
  hipMemsetAsync(counts, 0, (size_t)N * 4, stream);
  prep2<<<TB_T + TB_X + TB_E, 256, 0, stream>>>(x, W1, W2, W3, dst, counts, xh, w1, w2, w3);
  scan_kernel<<<1, 1024, 0, stream>>>(counts, row_ptr, cursor, N);
  scatter_kernel<<<(E + 255) / 256, 256, 0, stream>>>(src, dst, cursor, ssrc, E);

  const int RPG = 10;                         // ceil(79 row-blocks / 8 XCDs)
  const int AGG_GRID = 8 * ((N + 7) / 8);     // 8 chunks x node-groups (8 nodes/block)
  const int SM_GRID = (N + 15) / 16;          // 16 nodes per block

  // ---- layer 1 ----
  gemm_f16<0><<<8 * RPG * 8, 256, 0, stream>>>(xh, w1, Whf, N, 64, 8);
  att_kernel<4, 256, 1024, 256><<<N, 256, 0, stream>>>(Whf, a1, atts, attd, N);
  edge_softmax_csr<4><<<SM_GRID, 256, 0, stream>>>(row_ptr, ssrc, atts, attd, cbuf, dinv, N);
  aggregate_cat_chunk<0><<<AGG_GRID, 256, 0, stream>>>(row_ptr, ssrc, cbuf, dinv, Whf, nullptr, h1, N);

  // ---- layer 2 (aggregate emits hsum = h1 + elu(agg)) ----
  gemm_f16<0><<<8 * RPG * 8, 256, 0, stream>>>(h1, w2, Whf, N, 1024, 8);
  att_kernel<4, 256, 1024, 256><<<N, 256, 0, stream>>>(Whf, a2, atts, attd, N);
  edge_softmax_csr<4><<<SM_GRID, 256, 0, stream>>>(row_ptr, ssrc, atts, attd, cbuf, dinv, N);
  aggregate_cat_chunk<1><<<AGG_GRID, 256, 0, stream>>>(row_ptr, ssrc, cbuf, dinv, Whf, h1, hsum, N);

  // ---- layer 3 (padded head-stride 128; partials + reduce) ----
  gemm_f16<1><<<8 * RPG * 6, 256, 0, stream>>>(hsum, w3, Whf, N, 1024, 6);
  att_kernel<6, 121, 768, 128><<<N, 384, 0, stream>>>(Whf, a3, atts, attd, N);
  edge_softmax_csr<6><<<SM_GRID, 256, 0, stream>>>(row_ptr, ssrc, atts, attd, cbuf, dinv, N);
  aggregate_mean_chunk<<<AGG_GRID, 256, 0, stream>>>(row_ptr, ssrc, cbuf, dinv, Whf, part, N);
  reduce_mean<<<N, 128, 0, stream>>>(part, out, N);
}

// Round 17
// 263.230 us; speedup vs baseline: 1.1140x; 1.0020x over previous
//
#include <hip/hip_runtime.h>
#include <hip/hip_bf16.h>
#include <math.h>

#define NN 10000
#define NE 160000

typedef __attribute__((ext_vector_type(8))) _Float16 f16x8;
typedef __attribute__((ext_vector_type(4))) _Float16 f16x4;
typedef __attribute__((ext_vector_type(4))) float f32x4;

static __device__ __forceinline__ void gload_lds16(const _Float16* g, _Float16* l) {
  __builtin_amdgcn_global_load_lds((const __attribute__((address_space(1))) char*)g,
                                   (__attribute__((address_space(3))) char*)l, 16, 0, 0);
}

// ---------------- CSR build ----------------
__global__ __launch_bounds__(1024) void scan_kernel(const int* __restrict__ counts,
                                                    int* __restrict__ row_ptr,
                                                    int* __restrict__ cursor, int N) {
  __shared__ int sums[1024];
  int t = threadIdx.x;
  const int CH = (N + 1023) >> 10;
  int base = t * CH;
  int s = 0;
  for (int i = 0; i < CH; ++i) { int idx = base + i; if (idx < N) s += counts[idx]; }
  sums[t] = s;
  __syncthreads();
  for (int off = 1; off < 1024; off <<= 1) {
    int v = 0;
    if (t >= off) v = sums[t - off];
    __syncthreads();
    if (t >= off) sums[t] += v;
    __syncthreads();
  }
  int run = (t == 0) ? 0 : sums[t - 1];
  for (int i = 0; i < CH; ++i) {
    int idx = base + i;
    if (idx < N) { row_ptr[idx] = run; cursor[idx] = run; run += counts[idx]; }
  }
  if (t == 0) row_ptr[N] = sums[1023];
}

__global__ void scatter_kernel(const int* __restrict__ src, const int* __restrict__ dst,
                               int* __restrict__ cursor, int* __restrict__ ssrc, int E) {
  int e = blockIdx.x * blockDim.x + threadIdx.x;
  if (e < E) {
    int pos = atomicAdd(&cursor[dst[e]], 1);
    ssrc[pos] = src[e];
  }
}

// ---------------- prep2: tiled transposes + x copy + edge count + att projections ----------------
// wtilT layout [16][KP] f16: row j = side*H + h (side 0 = src, 1 = dst); rows >= 2H zero.
#define TB_W2 256
#define TB_W3 192
#define TB_W1 16
#define TB_T (TB_W2 + TB_W3 + TB_W1)          // 464
#define TB_X ((NN * 64) / 256)                // 2500
#define TB_E ((NE + 255) / 256)               // 625
#define WT1 (16 * 64)
#define WT2 (16 * 1024)
#define WT3 (16 * 1024)
#define TB_WT ((WT1 + WT2 + WT3) / 256)       // 132
__global__ __launch_bounds__(256) void prep2(const float* __restrict__ x,
                                             const float* __restrict__ W1,
                                             const float* __restrict__ a1,
                                             const float* __restrict__ W2,
                                             const float* __restrict__ a2,
                                             const float* __restrict__ W3,
                                             const float* __restrict__ a3,
                                             const int* __restrict__ dst,
                                             int* __restrict__ counts,
                                             _Float16* __restrict__ xh,
                                             _Float16* __restrict__ w1,
                                             _Float16* __restrict__ w2,
                                             _Float16* __restrict__ w3,
                                             _Float16* __restrict__ wt1,
                                             _Float16* __restrict__ wt2,
                                             _Float16* __restrict__ wt3) {
  int b = blockIdx.x;
  int t = threadIdx.x;
  if (b < TB_T) {
    const float* S;
    _Float16* D;
    int K, Nsrc, KP, k0, n0;
    if (b < TB_W2) {
      S = W2; D = w2; K = 1024; Nsrc = 1024; KP = 1024;
      k0 = (b & 15) * 64; n0 = (b >> 4) * 64;
    } else if (b < TB_W2 + TB_W3) {
      int bb = b - TB_W2;
      S = W3; D = w3; K = 1024; Nsrc = 726; KP = 1024;
      k0 = (bb & 15) * 64; n0 = (bb >> 4) * 64;
    } else {
      int bb = b - TB_W2 - TB_W3;
      S = W1; D = w1; K = 50; Nsrc = 1024; KP = 64;
      k0 = 0; n0 = bb * 64;
    }
    __shared__ float tile[64][65];
#pragma unroll
    for (int i = 0; i < 16; ++i) {
      int idx = i * 256 + t;
      int r = idx >> 6, c = idx & 63;
      int gk = k0 + r, gn = n0 + c;
      tile[r][c] = (gk < K && gn < Nsrc) ? S[(size_t)gk * Nsrc + gn] : 0.f;
    }
    __syncthreads();
#pragma unroll
    for (int i = 0; i < 16; ++i) {
      int idx = i * 256 + t;
      int r = idx >> 6, c = idx & 63;
      D[(size_t)(n0 + r) * KP + k0 + c] = (_Float16)tile[c][r];
    }
    return;
  }
  int i = (b - TB_T) * 256 + t;
  if (i < NN * 64) {
    int m = i >> 6, k = i & 63;
    xh[i] = (_Float16)(k < 50 ? x[m * 50 + k] : 0.f);
    return;
  }
  i -= NN * 64;
  if (i < NE) { atomicAdd(&counts[dst[i]], 1); return; }
  i -= NE;
  if (i < WT1) {                       // wtilT1 [16][64], H=4, F=256, K=50
    int j = i >> 6, k = i & 63;
    float v = 0.f;
    if (j < 8 && k < 50) {
      int h = j & 3, side = j >> 2;
      const float* wp = W1 + k * 1024 + h * 256;
      const float* ap = a1 + h * 512 + side * 256;
      float s = 0.f;
      for (int f = 0; f < 256; f += 4) {
        f32x4 wv = *(const f32x4*)&wp[f];
        f32x4 av = *(const f32x4*)&ap[f];
        s += wv.x * av.x + wv.y * av.y + wv.z * av.z + wv.w * av.w;
      }
      v = s;
    }
    wt1[i] = (_Float16)v;
    return;
  }
  i -= WT1;
  if (i < WT2) {                       // wtilT2 [16][1024], H=4, F=256, K=1024
    int j = i >> 10, k = i & 1023;
    float v = 0.f;
    if (j < 8) {
      int h = j & 3, side = j >> 2;
      const float* wp = W2 + k * 1024 + h * 256;
      const float* ap = a2 + h * 512 + side * 256;
      float s = 0.f;
      for (int f = 0; f < 256; f += 4) {
        f32x4 wv = *(const f32x4*)&wp[f];
        f32x4 av = *(const f32x4*)&ap[f];
        s += wv.x * av.x + wv.y * av.y + wv.z * av.z + wv.w * av.w;
      }
      v = s;
    }
    wt2[i] = (_Float16)v;
    return;
  }
  i -= WT2;
  if (i < WT3) {                       // wtilT3 [16][1024], H=6, F=121, K=1024
    int j = i >> 10, k = i & 1023;
    float v = 0.f;
    if (j < 12) {
      int h = (j < 6) ? j : j - 6;
      int side = (j < 6) ? 0 : 1;
      const float* wp = W3 + k * 726 + h * 121;
      const float* ap = a3 + h * 242 + side * 121;
      float s = 0.f;
#pragma unroll 11
      for (int f = 0; f < 121; ++f) s += wp[f] * ap[f];
      v = s;
    }
    wt3[i] = (_Float16)v;
    return;
  }
}

// ---------------- fp16 MFMA GEMM + fused att scores, XCD-swizzled, 128x128, BK=64 ----------------
// cblk==0 blocks: wc==0 waves also compute att = A @ wtilT (16-col MFMA tile, b-frag
// straight from global; shares a[mi] fragments). Epilogue: col<hh -> atts, <2hh -> attd.
template<int PAD121>
__global__ __launch_bounds__(256) void gemm_f16(const _Float16* __restrict__ A,
                                                const _Float16* __restrict__ B,
                                                const _Float16* __restrict__ wtilT,
                                                _Float16* __restrict__ C,
                                                float* __restrict__ atts,
                                                float* __restrict__ attd,
                                                int M, int KP, int NC, int hh) {
  int flat = blockIdx.x;
  int xcd = flat & 7;
  int slot = flat >> 3;
  int cblk = slot % NC;
  int rblk = (slot / NC) * 8 + xcd;
  const int m0 = rblk * 128;
  if (m0 >= M) return;
  const int n0 = cblk * 128;

  __shared__ _Float16 As[128 * 64];
  __shared__ _Float16 Bs[128 * 64];

  const int t = threadIdx.x;
  const int lane = t & 63;
  const int wid = t >> 6;
  const int wr = wid >> 1;
  const int wc = wid & 1;
  const int row_in = lane & 15;
  const int kgrp = lane >> 4;

  const int srow = wid * 32 + ((lane >> 3) & 7);
  const int sl7 = lane & 7;
  const bool do_att = (cblk == 0) && (wc == 0);

  f32x4 acc[4][4];
#pragma unroll
  for (int i = 0; i < 4; ++i)
#pragma unroll
    for (int j = 0; j < 4; ++j) acc[i][j] = (f32x4){0.f, 0.f, 0.f, 0.f};
  f32x4 acc_att[4];
#pragma unroll
  for (int i = 0; i < 4; ++i) acc_att[i] = (f32x4){0.f, 0.f, 0.f, 0.f};

  for (int k0 = 0; k0 < KP; k0 += 64) {
    if (k0) __syncthreads();
#pragma unroll
    for (int j = 0; j < 4; ++j) {
      int row = srow + j * 8;
      int gs = (sl7 ^ (row & 7)) * 8;
      int gm = m0 + row;
      if (gm >= M) gm = M - 1;
      _Float16* ldsA = &As[(wid * 32 + j * 8) * 64];
      _Float16* ldsB = &Bs[(wid * 32 + j * 8) * 64];
      gload_lds16(&A[(size_t)gm * KP + k0 + gs], ldsA);
      gload_lds16(&B[(size_t)(n0 + row) * KP + k0 + gs], ldsB);
    }
    __syncthreads();

#pragma unroll
    for (int ks = 0; ks < 2; ++ks) {
      f16x8 a[4], b[4];
#pragma unroll
      for (int mi = 0; mi < 4; ++mi) {
        int arow = wr * 64 + mi * 16 + row_in;
        int ps = ((kgrp + ks * 4) ^ (arow & 7)) * 8;
        a[mi] = *(const f16x8*)&As[arow * 64 + ps];
      }
#pragma unroll
      for (int ni = 0; ni < 4; ++ni) {
        int brow = wc * 64 + ni * 16 + row_in;
        int ps = ((kgrp + ks * 4) ^ (brow & 7)) * 8;
        b[ni] = *(const f16x8*)&Bs[brow * 64 + ps];
      }
#pragma unroll
      for (int mi = 0; mi < 4; ++mi)
#pragma unroll
        for (int ni = 0; ni < 4; ++ni)
          acc[mi][ni] = __builtin_amdgcn_mfma_f32_16x16x32_f16(a[mi], b[ni], acc[mi][ni], 0, 0, 0);
      if (do_att) {
        f16x8 bt = *(const f16x8*)&wtilT[(size_t)row_in * KP + k0 + ks * 32 + kgrp * 8];
#pragma unroll
        for (int mi = 0; mi < 4; ++mi)
          acc_att[mi] = __builtin_amdgcn_mfma_f32_16x16x32_f16(a[mi], bt, acc_att[mi], 0, 0, 0);
      }
    }
  }

#pragma unroll
  for (int mi = 0; mi < 4; ++mi) {
#pragma unroll
    for (int ni = 0; ni < 4; ++ni) {
      int gn = n0 + wc * 64 + ni * 16 + row_in;
#pragma unroll
      for (int j = 0; j < 4; ++j) {
        int gm = m0 + wr * 64 + mi * 16 + kgrp * 4 + j;
        if (gm >= M) continue;
        if (PAD121) {
          if (gn < 726) {
            int h = gn / 121;
            int pc = h * 128 + (gn - h * 121);
            C[(size_t)gm * 768 + pc] = (_Float16)acc[mi][ni][j];
          }
        } else {
          C[(size_t)gm * 1024 + gn] = (_Float16)acc[mi][ni][j];
        }
      }
    }
  }
  if (do_att) {
    int col = row_in;
#pragma unroll
    for (int mi = 0; mi < 4; ++mi) {
#pragma unroll
      for (int j = 0; j < 4; ++j) {
        int gm = m0 + wr * 64 + mi * 16 + kgrp * 4 + j;
        if (gm >= M) continue;
        float v = acc_att[mi][j];
        if (col < hh) atts[(size_t)gm * hh + col] = v;
        else if (col < 2 * hh) attd[(size_t)gm * hh + col - hh] = v;
      }
    }
  }
}

// ---------------- fused CSR edge softmax: 16 lanes/node, 16 nodes per block ----------------
template<int H>
__global__ __launch_bounds__(256) void edge_softmax_csr(const int* __restrict__ row_ptr,
                                                        const int* __restrict__ ssrc,
                                                        const float* __restrict__ att_s,
                                                        const float* __restrict__ att_d,
                                                        float* __restrict__ cbuf,
                                                        float* __restrict__ dinv, int N) {
  int n = blockIdx.x * 16 + (threadIdx.x >> 4);
  if (n >= N) return;
  int lane = threadIdx.x & 15;
  int beg = row_ptr[n], end = row_ptr[n + 1];

  float ad[H];
  if (H == 4) {
    f32x4 v = *(const f32x4*)&att_d[n * 4];
    ad[0] = v.x; ad[1] = v.y; ad[2] = v.z; ad[3] = v.w;
  } else {
#pragma unroll
    for (int h = 0; h < H; ++h) ad[h] = att_d[n * H + h];
  }

  float m[H];
#pragma unroll
  for (int h = 0; h < H; ++h) m[h] = -1e30f;
  for (int k = beg + lane; k < end; k += 16) {
    int s = ssrc[k];
    float as[H];
    if (H == 4) {
      f32x4 v = *(const f32x4*)&att_s[s * 4];
      as[0] = v.x; as[1] = v.y; as[2] = v.z; as[3] = v.w;
    } else {
#pragma unroll
      for (int h = 0; h < H; ++h) as[h] = att_s[s * H + h];
    }
#pragma unroll
    for (int h = 0; h < H; ++h) {
      float xv = as[h] + ad[h];
      float l = xv >= 0.f ? xv : 0.2f * xv;
      m[h] = fmaxf(m[h], l);
    }
  }
#pragma unroll
  for (int h = 0; h < H; ++h)
#pragma unroll
    for (int off = 8; off > 0; off >>= 1) m[h] = fmaxf(m[h], __shfl_xor(m[h], off));

  float sum[H];
#pragma unroll
  for (int h = 0; h < H; ++h) sum[h] = 0.f;
  for (int k = beg + lane; k < end; k += 16) {
    int s = ssrc[k];
    float as[H];
    if (H == 4) {
      f32x4 v = *(const f32x4*)&att_s[s * 4];
      as[0] = v.x; as[1] = v.y; as[2] = v.z; as[3] = v.w;
    } else {
#pragma unroll
      for (int h = 0; h < H; ++h) as[h] = att_s[s * H + h];
    }
    float ev[H];
#pragma unroll
    for (int h = 0; h < H; ++h) {
      float xv = as[h] + ad[h];
      float l = xv >= 0.f ? xv : 0.2f * xv;
      ev[h] = __expf(l - m[h]);
      sum[h] += ev[h];
    }
    if (H == 4) {
      *(f32x4*)&cbuf[(size_t)k * 4] = (f32x4){ev[0], ev[1], ev[2], ev[3]};
    } else {
#pragma unroll
      for (int h = 0; h < H; ++h) cbuf[(size_t)k * H + h] = ev[h];
    }
  }
#pragma unroll
  for (int h = 0; h < H; ++h) {
#pragma unroll
    for (int off = 8; off > 0; off >>= 1) sum[h] += __shfl_xor(sum[h], off);
  }
  if (lane < H) dinv[n * H + lane] = 1.f / (sum[lane] + 1e-16f);
}

// ---------------- chunked aggregate, concat layers (H=4,F=256): 32 lanes/node ----------------
template<int MODE>
__global__ __launch_bounds__(256) void aggregate_cat_chunk(const int* __restrict__ row_ptr,
                                                           const int* __restrict__ ssrc,
                                                           const float* __restrict__ cbuf,
                                                           const float* __restrict__ dinv,
                                                           const _Float16* __restrict__ Whb,
                                                           const _Float16* __restrict__ h1,
                                                           _Float16* __restrict__ outv, int N) {
  int b = blockIdx.x;
  int chunk = b & 7;
  int group = b >> 3;
  int n = group * 8 + (threadIdx.x >> 5);
  if (n >= N) return;
  int l32 = threadIdx.x & 31;
  int half = l32 >> 4;
  int tt = l32 & 15;
  int idx = chunk * 128 + tt * 8;
  int h = chunk >> 1;
  float inv = dinv[n * 4 + h];

  float acc[8] = {};
  int beg = row_ptr[n], end = row_ptr[n + 1];
  int k = beg + half;
  for (; k + 6 < end; k += 8) {
    int s0 = ssrc[k], s1 = ssrc[k + 2], s2 = ssrc[k + 4], s3 = ssrc[k + 6];
    float c0 = cbuf[(size_t)k * 4 + h];
    float c1 = cbuf[(size_t)(k + 2) * 4 + h];
    float c2 = cbuf[(size_t)(k + 4) * 4 + h];
    float c3 = cbuf[(size_t)(k + 6) * 4 + h];
    f16x8 w0 = *(const f16x8*)&Whb[(size_t)s0 * 1024 + idx];
    f16x8 w1 = *(const f16x8*)&Whb[(size_t)s1 * 1024 + idx];
    f16x8 w2 = *(const f16x8*)&Whb[(size_t)s2 * 1024 + idx];
    f16x8 w3 = *(const f16x8*)&Whb[(size_t)s3 * 1024 + idx];
#pragma unroll
    for (int j = 0; j < 8; ++j) {
      acc[j] += c0 * (float)w0[j];
      acc[j] += c1 * (float)w1[j];
      acc[j] += c2 * (float)w2[j];
      acc[j] += c3 * (float)w3[j];
    }
  }
  for (; k < end; k += 2) {
    int s0 = ssrc[k];
    float c0 = cbuf[(size_t)k * 4 + h];
    f16x8 w0 = *(const f16x8*)&Whb[(size_t)s0 * 1024 + idx];
#pragma unroll
    for (int j = 0; j < 8; ++j) acc[j] += c0 * (float)w0[j];
  }
#pragma unroll
  for (int j = 0; j < 8; ++j) acc[j] += __shfl_xor(acc[j], 16);

  if (half == 0) {
    size_t o = (size_t)n * 1024 + idx;
    f16x8 r1;
    if (MODE == 1) r1 = *(const f16x8*)&h1[o];
    f16x8 vo;
#pragma unroll
    for (int j = 0; j < 8; ++j) {
      float v = acc[j] * inv;
      v = v > 0.f ? v : expm1f(v);
      if (MODE == 1) v += (float)r1[j];
      vo[j] = (_Float16)v;
    }
    *(f16x8*)&outv[o] = vo;
  }
}

// ---------------- chunked aggregate, mean layer: chunk = head (6 of 8), 32 lanes/node ----------------
__global__ __launch_bounds__(256) void aggregate_mean_chunk(const int* __restrict__ row_ptr,
                                                            const int* __restrict__ ssrc,
                                                            const float* __restrict__ cbuf,
                                                            const float* __restrict__ dinv,
                                                            const _Float16* __restrict__ Whb,
                                                            float* __restrict__ part, int N) {
  int b = blockIdx.x;
  int h = b & 7;
  if (h >= 6) return;
  int n = (b >> 3) * 8 + (threadIdx.x >> 5);
  if (n >= N) return;
  int l32 = threadIdx.x & 31;
  int half = l32 >> 4;
  int tt = l32 & 15;
  int base = h * 128 + tt * 8;
  float inv = dinv[n * 6 + h];

  float acc[8] = {};
  int beg = row_ptr[n], end = row_ptr[n + 1];
  int k = beg + half;
  for (; k + 6 < end; k += 8) {
    int s0 = ssrc[k], s1 = ssrc[k + 2], s2 = ssrc[k + 4], s3 = ssrc[k + 6];
    float c0 = cbuf[(size_t)k * 6 + h];
    float c1 = cbuf[(size_t)(k + 2) * 6 + h];
    float c2 = cbuf[(size_t)(k + 4) * 6 + h];
    float c3 = cbuf[(size_t)(k + 6) * 6 + h];
    f16x8 w0 = *(const f16x8*)&Whb[(size_t)s0 * 768 + base];
    f16x8 w1 = *(const f16x8*)&Whb[(size_t)s1 * 768 + base];
    f16x8 w2 = *(const f16x8*)&Whb[(size_t)s2 * 768 + base];
    f16x8 w3 = *(const f16x8*)&Whb[(size_t)s3 * 768 + base];
#pragma unroll
    for (int j = 0; j < 8; ++j) {
      acc[j] += c0 * (float)w0[j];
      acc[j] += c1 * (float)w1[j];
      acc[j] += c2 * (float)w2[j];
      acc[j] += c3 * (float)w3[j];
    }
  }
  for (; k < end; k += 2) {
    int s0 = ssrc[k];
    float c0 = cbuf[(size_t)k * 6 + h];
    f16x8 w0 = *(const f16x8*)&Whb[(size_t)s0 * 768 + base];
#pragma unroll
    for (int j = 0; j < 8; ++j) acc[j] += c0 * (float)w0[j];
  }
#pragma unroll
  for (int j = 0; j < 8; ++j) acc[j] += __shfl_xor(acc[j], 16);

  if (half == 0) {
    float* p = &part[(size_t)n * 768 + base];
    *(f32x4*)&p[0] = (f32x4){acc[0] * inv, acc[1] * inv, acc[2] * inv, acc[3] * inv};
    *(f32x4*)&p[4] = (f32x4){acc[4] * inv, acc[5] * inv, acc[6] * inv, acc[7] * inv};
  }
}

// ---------------- reduce 6 head-slices -> out[n][121] ----------------
__global__ __launch_bounds__(128) void reduce_mean(const float* __restrict__ part,
                                                   float* __restrict__ out, int N) {
  int n = blockIdx.x;
  int f = threadIdx.x;
  if (f >= 121) return;
  const float* p = &part[(size_t)n * 768];
  float s = 0.f;
#pragma unroll
  for (int h = 0; h < 6; ++h) s += p[h * 128 + f];
  out[(size_t)n * 121 + f] = s * (1.0f / 6.0f);
}

extern "C" void kernel_launch(void* const* d_in, const int* in_sizes, int n_in,
                              void* d_out, int out_size, void* d_ws, size_t ws_size,
                              hipStream_t stream) {
  const float* x  = (const float*)d_in[0];
  const int* eidx = (const int*)d_in[1];
  const float* W1 = (const float*)d_in[2];
  const float* a1 = (const float*)d_in[3];
  const float* W2 = (const float*)d_in[4];
  const float* a2 = (const float*)d_in[5];
  const float* W3 = (const float*)d_in[6];
  const float* a3 = (const float*)d_in[7];
  float* out = (float*)d_out;

  const int N = NN, E = NE;
  const int* src = eidx;
  const int* dst = eidx + E;

  char* ws = (char*)d_ws;
  size_t off = 0;
  auto alloc = [&](size_t bytes) -> void* {
    void* p = ws + off;
    off += (bytes + 255) & ~(size_t)255;
    return p;
  };
  _Float16* Whf  = (_Float16*)alloc((size_t)N * 1024 * 2);
  _Float16* h1   = (_Float16*)alloc((size_t)N * 1024 * 2);
  _Float16* hsum = (_Float16*)alloc((size_t)N * 1024 * 2);
  _Float16* xh   = (_Float16*)alloc((size_t)N * 64 * 2);
  _Float16* w1   = (_Float16*)alloc((size_t)1024 * 64 * 2);
  _Float16* w2   = (_Float16*)alloc((size_t)1024 * 1024 * 2);
  _Float16* w3   = (_Float16*)alloc((size_t)768 * 1024 * 2);
  _Float16* wt1  = (_Float16*)alloc((size_t)16 * 64 * 2);
  _Float16* wt2  = (_Float16*)alloc((size_t)16 * 1024 * 2);
  _Float16* wt3  = (_Float16*)alloc((size_t)16 * 1024 * 2);
  float* cbuf  = (float*)alloc((size_t)E * 6 * 4);
  float* part  = (float*)alloc((size_t)N * 768 * 4);
  float* atts  = (float*)alloc((size_t)N * 6 * 4);
  float* attd  = (float*)alloc((size_t)N * 6 * 4);
  float* dinv  = (float*)alloc((size_t)N * 6 * 4);
  int* counts  = (int*)alloc((size_t)N * 4);
  int* row_ptr = (int*)alloc((size_t)(N + 1) * 4);
  int* cursor  = (int*)alloc((size_t)N * 4);
  int* ssrc    = (int*)alloc((size_t)E * 4);

  // ---- prep (transposes + x + edge count + att projections) and CSR ----
  hipMemsetAsync(counts, 0, (size_t)N * 4, stream);
  prep2<<<TB_T + TB_X + TB_E + TB_WT, 256, 0, stream>>>(x, W1, a1, W2, a2, W3, a3,
                                                        dst, counts, xh, w1, w2, w3,
                                                        wt1, wt2, wt3);
  scan_kernel<<<1, 1024, 0, stream>>>(counts, row_ptr, cursor, N);
  scatter_kernel<<<(E + 255) / 256, 256, 0, stream>>>(src, dst, cursor, ssrc, E);

  const int RPG = 10;                         // ceil(79 row-blocks / 8 XCDs)
  const int AGG_GRID = 8 * ((N + 7) / 8);     // 8 chunks x node-groups (8 nodes/block)
  const int SM_GRID = (N + 15) / 16;          // 16 nodes per block

  // ---- layer 1 (GEMM computes att in-pass) ----
  gemm_f16<0><<<8 * RPG * 8, 256, 0, stream>>>(xh, w1, wt1, Whf, atts, attd, N, 64, 8, 4);
  edge_softmax_csr<4><<<SM_GRID, 256, 0, stream>>>(row_ptr, ssrc, atts, attd, cbuf, dinv, N);
  aggregate_cat_chunk<0><<<AGG_GRID, 256, 0, stream>>>(row_ptr, ssrc, cbuf, dinv, Whf, nullptr, h1, N);

  // ---- layer 2 (aggregate emits hsum = h1 + elu(agg)) ----
  gemm_f16<0><<<8 * RPG * 8, 256, 0, stream>>>(h1, w2, wt2, Whf, atts, attd, N, 1024, 8, 4);
  edge_softmax_csr<4><<<SM_GRID, 256, 0, stream>>>(row_ptr, ssrc, atts, attd, cbuf, dinv, N);
  aggregate_cat_chunk<1><<<AGG_GRID, 256, 0, stream>>>(row_ptr, ssrc, cbuf, dinv, Whf, h1, hsum, N);

  // ---- layer 3 (padded head-stride 128; partials + reduce) ----
  gemm_f16<1><<<8 * RPG * 6, 256, 0, stream>>>(hsum, w3, wt3, Whf, atts, attd, N, 1024, 6, 6);
  edge_softmax_csr<6><<<SM_GRID, 256, 0, stream>>>(row_ptr, ssrc, atts, attd, cbuf, dinv, N);
  aggregate_mean_chunk<<<AGG_GRID, 256, 0, stream>>>(row_ptr, ssrc, cbuf, dinv, Whf, part, N);
  reduce_mean<<<N, 128, 0, stream>>>(part, out, N);
}